// Round 13
// baseline (409.139 us; speedup 1.0000x reference)
//
#include <hip/hip_runtime.h>
#include <hip/hip_bf16.h>
#include <stdint.h>

#define AS1 __attribute__((address_space(1)))
#define AS3 __attribute__((address_space(3)))

typedef unsigned short ushort_t;
typedef __attribute__((ext_vector_type(8))) short short8;
typedef __attribute__((ext_vector_type(4))) float floatx4;
typedef __attribute__((ext_vector_type(16))) float floatx16;
typedef __attribute__((ext_vector_type(2))) unsigned int uint2v;

// ---------- helpers ----------
__device__ __forceinline__ ushort_t f2b(float f) {
    union { float f; unsigned int i; } x; x.f = f;
    unsigned int r = x.i + 0x7fffu + ((x.i >> 16) & 1u);   // RNE
    return (ushort_t)(r >> 16);
}
__device__ __forceinline__ float b2f(ushort_t u) {
    union { unsigned int i; float f; } x; x.i = ((unsigned int)u) << 16; return x.f;
}
// async global->LDS, 16B per lane. LDS dest must be wave-uniform base + lane*16.
__device__ __forceinline__ void gl2lds16(const void* g, void* l) {
    __builtin_amdgcn_global_load_lds(
        (const AS1 unsigned int*)g,
        (AS3 unsigned int*)l,
        16, 0, 0);
}
// swap: a.hi-lanes <-> b.lo-lanes (both updated)
__device__ __forceinline__ void plswap(unsigned& a, unsigned& b) {
#if __has_builtin(__builtin_amdgcn_permlane32_swap)
    uint2v r = __builtin_amdgcn_permlane32_swap(a, b, false, false);
    a = r.x; b = r.y;
#else
    asm volatile("v_permlane32_swap_b32 %0, %1" : "+v"(a), "+v"(b));
#endif
}

static constexpr int CCH = 512;
static constexpr int NSP = 4096;   // 64*64 spatial
static constexpr int NG  = 32;

// ---------- kernel 1: prep = weight conversion (y<4) + GroupNorm stats (y==4) ----------
// y in 0..3: fp32 weights -> bf16 (Q pre-scaled by 512^-0.5); builds concat QK bias.
// y == 4, x < 128: GroupNorm stats over group x (one 65536-elem slab of x).
__global__ __launch_bounds__(256) void prep(const float* __restrict__ q,
                                            const float* __restrict__ k,
                                            const float* __restrict__ v,
                                            const float* __restrict__ p,
                                            const float* __restrict__ qb,
                                            const float* __restrict__ kb,
                                            ushort_t* __restrict__ out,
                                            float* __restrict__ sqb,
                                            const float* __restrict__ x,
                                            float* __restrict__ mean,
                                            float* __restrict__ rstd) {
    __shared__ float r1[4], r2[4];
    const int t = threadIdx.x;
    if (blockIdx.y == 4) {
        if (blockIdx.x >= 128) return;
        const long base = (long)blockIdx.x * 65536;
        float s1 = 0.f, s2 = 0.f;
        for (int i = t * 8; i < 65536; i += 256 * 8) {
            float4 a = *(const float4*)(x + base + i);
            float4 b = *(const float4*)(x + base + i + 4);
            s1 += a.x + a.y + a.z + a.w + b.x + b.y + b.z + b.w;
            s2 += a.x * a.x + a.y * a.y + a.z * a.z + a.w * a.w
                + b.x * b.x + b.y * b.y + b.z * b.z + b.w * b.w;
        }
#pragma unroll
        for (int o = 32; o; o >>= 1) { s1 += __shfl_xor(s1, o, 64); s2 += __shfl_xor(s2, o, 64); }
        const int lane = t & 63, wave = t >> 6;
        if (!lane) { r1[wave] = s1; r2[wave] = s2; }
        __syncthreads();
        if (!t) {
            float S1 = r1[0] + r1[1] + r1[2] + r1[3];
            float S2 = r2[0] + r2[1] + r2[2] + r2[3];
            float mu = S1 * (1.f / 65536.f);
            float var = S2 * (1.f / 65536.f) - mu * mu;
            mean[blockIdx.x] = mu;
            rstd[blockIdx.x] = rsqrtf(var + 1e-5f);
        }
        return;
    }
    const float scl = 0.044194173824159216f;  // 512^-0.5
    const float* srcs[4] = { q, k, v, p };
    const float* s = srcs[blockIdx.y];
    const float m = (blockIdx.y == 0) ? scl : 1.f;
    const long i = ((long)blockIdx.x * 256 + t) * 4;
    float4 f = *(const float4*)(s + i);
    ushort_t o[4] __attribute__((aligned(8)));
    o[0] = f2b(f.x * m); o[1] = f2b(f.y * m); o[2] = f2b(f.z * m); o[3] = f2b(f.w * m);
    *(ushort4*)(out + (long)blockIdx.y * 262144 + i) = *(ushort4*)o;
    if (blockIdx.y == 0 && blockIdx.x == 0 && t < 128) {
        const int j = t * 4;
        float4 b = *(const float4*)(qb + j);
        sqb[j] = b.x * scl; sqb[j + 1] = b.y * scl; sqb[j + 2] = b.z * scl; sqb[j + 3] = b.w * scl;
    }
    if (blockIdx.y == 1 && blockIdx.x == 0 && t < 128) {
        const int j = t * 4;
        float4 b = *(const float4*)(kb + j);
        sqb[512 + j] = b.x; sqb[513 + j] = b.y; sqb[514 + j] = b.z; sqb[515 + j] = b.w;
    }
}

// ---------- kernel 3: normalize + transpose ----------
__global__ __launch_bounds__(256) void norm_transpose(const float* __restrict__ x,
                                                      const float* __restrict__ gw,
                                                      const float* __restrict__ gb,
                                                      const float* __restrict__ mean,
                                                      const float* __restrict__ rstd,
                                                      ushort_t* __restrict__ ht) {
    __shared__ ushort_t tile[64 * 65];
    const int b = blockIdx.z, c0 = blockIdx.y * 64, n0 = blockIdx.x * 64;
    const int t = threadIdx.x;
    const float* xb = x + ((long)b * CCH + c0) * NSP + n0;
#pragma unroll
    for (int p = 0; p < 2; ++p) {
        int li = p * 2048 + t * 8;
        int cl = li >> 6, nl = li & 63;
        int c = c0 + cl, g = c >> 4;
        float mu = mean[b * NG + g], rs = rstd[b * NG + g];
        float w  = gw[c] * rs;
        float bb = gb[c] - mu * w;
        float4 a = *(const float4*)(xb + (long)cl * NSP + nl);
        float4 d = *(const float4*)(xb + (long)cl * NSP + nl + 4);
        float f[8] = { a.x, a.y, a.z, a.w, d.x, d.y, d.z, d.w };
#pragma unroll
        for (int j = 0; j < 8; ++j) tile[cl * 65 + nl + j] = f2b(f[j] * w + bb);
    }
    __syncthreads();
#pragma unroll
    for (int p = 0; p < 2; ++p) {
        int li = p * 2048 + t * 8;
        int nl = li >> 6, cl = li & 63;
        ushort_t v[8] __attribute__((aligned(16)));
#pragma unroll
        for (int j = 0; j < 8; ++j) v[j] = tile[(cl + j) * 65 + nl];
        *(uint4*)(ht + ((long)b * NSP + n0 + nl) * CCH + c0 + cl) = *(uint4*)v;
    }
}

// ---------- GEMM: C[m][n] = scale * sum_k A[m][k]*B[n][k] (+bias)(+resid) ----------
// QK2: dual-output routing (n<512 -> Cp, else Cp2 at n-512); block-uniform branch.
template <int BIAS, int OUTF32, int RES, int QK2>
__global__ __launch_bounds__(256, 2) void gemm_tn(
    const ushort_t* __restrict__ A, int lda, long sA,
    const ushort_t* __restrict__ B, int ldb, long sB,
    void* __restrict__ Cp, int ldc, long sC,
    const float* __restrict__ bias,
    const float* __restrict__ resid, long sR,
    float scale, int K,
    void* __restrict__ Cp2) {
    __shared__ short As[128 * 32];
    __shared__ short Bs[128 * 32];
    const int t = threadIdx.x;
    const int lane = t & 63, wave = t >> 6;
    const long bz = blockIdx.z;
    const int m0 = blockIdx.y * 128, n0 = blockIdx.x * 128;

    const ushort_t* Ab = A + bz * sA + (long)(m0 + (t >> 2)) * lda + (t & 3) * 8;
    const ushort_t* Bb = B + bz * sB + (long)(n0 + (t >> 2)) * ldb + (t & 3) * 8;
    short* la = As + t * 8;
    short* lb = Bs + t * 8;

    const int wm = (wave & 1) * 64, wn = (wave >> 1) * 64;
    const int lm = lane & 15, lk = (lane >> 4) * 8;
    const short* pa = As + (wm + lm) * 32 + lk;
    const short* pb = Bs + (wn + lm) * 32 + lk;

    floatx4 acc[4][4];
#pragma unroll
    for (int i = 0; i < 4; ++i)
#pragma unroll
        for (int j = 0; j < 4; ++j) acc[i][j] = (floatx4){0.f, 0.f, 0.f, 0.f};

    for (int k0 = 0; k0 < K; k0 += 32) {
        __syncthreads();
        gl2lds16(Ab, la);
        gl2lds16(Ab + 64 * (long)lda, la + 64 * 32);
        gl2lds16(Bb, lb);
        gl2lds16(Bb + 64 * (long)ldb, lb + 64 * 32);
        Ab += 32; Bb += 32;
        __builtin_amdgcn_s_waitcnt(0);
        __syncthreads();
        short8 af[4], bfr[4];
#pragma unroll
        for (int i = 0; i < 4; ++i) af[i]  = *(const short8*)(pa + i * 16 * 32);
#pragma unroll
        for (int i = 0; i < 4; ++i) bfr[i] = *(const short8*)(pb + i * 16 * 32);
#pragma unroll
        for (int mi = 0; mi < 4; ++mi)
#pragma unroll
            for (int ni = 0; ni < 4; ++ni)
                acc[mi][ni] = __builtin_amdgcn_mfma_f32_16x16x32_bf16(af[mi], bfr[ni], acc[mi][ni], 0, 0, 0);
    }

    const int row4 = (lane >> 4) * 4;
    const int ncol = lane & 15;
#pragma unroll
    for (int mi = 0; mi < 4; ++mi) {
#pragma unroll
        for (int ni = 0; ni < 4; ++ni) {
            const int n = n0 + wn + ni * 16 + ncol;
            float bn = (BIAS == 2) ? bias[n] : 0.f;
#pragma unroll
            for (int r = 0; r < 4; ++r) {
                const int m = m0 + wm + mi * 16 + row4 + r;
                float v = acc[mi][ni][r] * scale;
                if (BIAS == 1) v += bias[m];
                if (BIAS == 2) v += bn;
                if (RES) v += resid[bz * sR + (long)m * ldc + n];
                if (QK2) {
                    const long idx = bz * sC + (long)m * ldc + (n & 511);
                    if (n < 512) ((ushort_t*)Cp)[idx]  = f2b(v);
                    else         ((ushort_t*)Cp2)[idx] = f2b(v);
                } else {
                    const long idx = bz * sC + (long)m * ldc + n;
                    if (OUTF32) ((float*)Cp)[idx] = v;
                    else        ((ushort_t*)Cp)[idx] = f2b(v);
                }
            }
        }
    }
}

// ---------- fused flash attention v9 + in-kernel split merge ----------
// K-loop byte-identical to v9 (measured 194 us). After the partial-O write, the
// two blocks of each (batch, row-group) pair rendezvous via a device-scope flag
// (split-K fixup pattern: per-thread __threadfence release -> barrier -> t0
// atomicAdd; second arriver acquires and merges its 128-row slab). Replaces the
// separate 4096-block merge_splits dispatch; merge overlaps tail of other blocks.
__global__ __launch_bounds__(256, 1) void flash_attn(const ushort_t* __restrict__ Qt,
                                                     const ushort_t* __restrict__ Kt,
                                                     const ushort_t* __restrict__ V,
                                                     ushort_t* __restrict__ pO0,
                                                     ushort_t* __restrict__ pO1,
                                                     float* __restrict__ ml,
                                                     int* __restrict__ flags) {
    __shared__ short Klds[2 * 16384];     // 2 x 32 KB: row j = 64 granules, granule g holds global g^(j&15)
    __shared__ short Vlds[2 * 16384];     // 2 x 32 KB: [d 0..511][32 j], granule mv holds global mv^((d>>1)&3)
    __shared__ int arrived;
    const int t = threadIdx.x;
    const int lane = t & 63, wave = t >> 6;
    const int l31 = lane & 31, hi = lane >> 5;
    const int blk = blockIdx.x;
    const int xcd = blk & 7;
    const int bb = xcd >> 1;
    const int split = xcd & 1;
    const int rg = blk >> 3;
    const int rows0 = rg * 128 + wave * 32;
    const int j_lo = split * 2048;

    // Q B-frags: B[n=row=l31][k=s*16+hi*8+e], 32 x short8 = 128 VGPR
    const ushort_t* Qb = Qt + ((long)bb * NSP + rows0 + l31) * CCH + hi * 8;
    short8 qf[32];
#pragma unroll
    for (int s = 0; s < 32; ++s) qf[s] = *(const short8*)(Qb + s * 16);

    floatx16 acc[16];
#pragma unroll
    for (int i = 0; i < 16; ++i)
        acc[i] = (floatx16){0.f,0.f,0.f,0.f,0.f,0.f,0.f,0.f,0.f,0.f,0.f,0.f,0.f,0.f,0.f,0.f};
    float lsum = 0.f;

    const ushort_t* KtB = Kt + (long)bb * NSP * CCH;   // [4096][512]
    const ushort_t* Vb  = V + (long)bb * NSP * CCH;    // [512][4096]

#define STAGE_K(buf, J0)                                                          \
    {                                                                             \
        short* kb_ = Klds + (buf) * 16384;                                        \
        _Pragma("unroll")                                                         \
        for (int i_ = 0; i_ < 8; ++i_) {                                          \
            const int ch_ = i_ * 256 + t;                                         \
            const int jr_ = ch_ >> 6, m_ = ch_ & 63;                              \
            const int ms_ = m_ ^ (jr_ & 15);                                      \
            gl2lds16(KtB + (long)((J0) + jr_) * CCH + ms_ * 8, kb_ + ch_ * 8);    \
        }                                                                         \
    }
#define STAGE_V(buf, J0)                                                          \
    {                                                                             \
        short* vb_ = Vlds + (buf) * 16384;                                        \
        _Pragma("unroll")                                                         \
        for (int i_ = 0; i_ < 8; ++i_) {                                          \
            const int g_ = i_ * 256 + t;                                          \
            const int d_ = g_ >> 2, mv_ = g_ & 3;                                 \
            const int js_ = (mv_ ^ ((d_ >> 1) & 3)) * 8;                          \
            gl2lds16(Vb + (long)d_ * NSP + (J0) + js_, vb_ + g_ * 8);             \
        }                                                                         \
    }

    // softmax on sS -> PA0/PA1 (j 0..15 / 16..31 slices), updates lsum
#define SOFTMAX_PACK(sS, PA0, PA1)                                                \
    {                                                                             \
        float pv_[16];                                                            \
        _Pragma("unroll")                                                         \
        for (int r = 0; r < 16; ++r) { pv_[r] = __expf((sS)[r] - 12.f); lsum += pv_[r]; } \
        unsigned pk[8];                                                           \
        _Pragma("unroll")                                                         \
        for (int g = 0; g < 4; ++g) {                                             \
            asm("v_cvt_pk_bf16_f32 %0, %1, %2" : "=v"(pk[2 * g])     : "v"(pv_[4 * g]),     "v"(pv_[4 * g + 1])); \
            asm("v_cvt_pk_bf16_f32 %0, %1, %2" : "=v"(pk[2 * g + 1]) : "v"(pv_[4 * g + 2]), "v"(pv_[4 * g + 3])); \
        }                                                                         \
        plswap(pk[0], pk[2]);                                                     \
        plswap(pk[1], pk[3]);                                                     \
        plswap(pk[4], pk[6]);                                                     \
        plswap(pk[5], pk[7]);                                                     \
        union { unsigned u[4]; short8 s8; } uA_, uB_;                             \
        uA_.u[0] = pk[0]; uA_.u[1] = pk[1]; uA_.u[2] = pk[2]; uA_.u[3] = pk[3];   \
        uB_.u[0] = pk[4]; uB_.u[1] = pk[5]; uB_.u[2] = pk[6]; uB_.u[3] = pk[7];   \
        (PA0) = uA_.s8; (PA1) = uB_.s8;                                           \
    }

    STAGE_K(0, j_lo);
    STAGE_V(0, j_lo);
    STAGE_K(1, j_lo + 32);          // K one tile ahead
    __builtin_amdgcn_s_waitcnt(0);
    __syncthreads();

    // K read swizzle: granule for k-chunk s = (2s+hi) ^ (l31&15) = (4*s2 [+2]) ^ exr
    const int exr = (l31 & 15) ^ hi;
    const short* kroot = Klds + l31 * 512;
    const int cv = (l31 >> 1) & 3;          // V read swizzle
    const int voff0 = l31 * 32 + ((hi ^ cv) << 3);
    const int voff1 = l31 * 32 + (((2 + hi) ^ cv) << 3);

    // ---- prologue: S(0) from K buf 0 ----
    floatx16 sS = (floatx16){0.f,0.f,0.f,0.f,0.f,0.f,0.f,0.f,0.f,0.f,0.f,0.f,0.f,0.f,0.f,0.f};
#pragma unroll
    for (int s2 = 0; s2 < 16; ++s2) {
        short8 k0 = *(const short8*)(kroot + (((4 * s2)     ^ exr) << 3));
        short8 k1 = *(const short8*)(kroot + (((4 * s2 + 2) ^ exr) << 3));
        sS = __builtin_amdgcn_mfma_f32_32x32x16_bf16(k0, qf[2 * s2],     sS, 0, 0, 0);
        sS = __builtin_amdgcn_mfma_f32_32x32x16_bf16(k1, qf[2 * s2 + 1], sS, 0, 0, 0);
    }
    __syncthreads();                 // all waves done with K buf 0 -> restageable

    int j0 = j_lo;
    for (int tile = 0; tile < 63; ++tile) {
        const int cur = tile & 1, nxt = cur ^ 1;
        if (tile < 62) STAGE_K(cur, j0 + 64);    // K(t+2) -> slot of K(t)
        STAGE_V(nxt, j0 + 32);                   // V(t+1) -> slot of V(t-1)

        short8 PA0, PA1;
        SOFTMAX_PACK(sS, PA0, PA1);

        // ---- interleaved: PV(t) from V[cur]  ||  QK(t+1) from K[nxt] ----
        const short* kp  = kroot + nxt * 16384;
        const short* vp0 = Vlds + cur * 16384 + voff0;
        const short* vp1 = Vlds + cur * 16384 + voff1;
        floatx16 nS = (floatx16){0.f,0.f,0.f,0.f,0.f,0.f,0.f,0.f,0.f,0.f,0.f,0.f,0.f,0.f,0.f,0.f};
#pragma unroll
        for (int i = 0; i < 16; ++i) {
            short8 k0 = *(const short8*)(kp + (((4 * i)     ^ exr) << 3));
            short8 v0 = *(const short8*)(vp0 + i * 1024);
            nS = __builtin_amdgcn_mfma_f32_32x32x16_bf16(k0, qf[2 * i], nS, 0, 0, 0);
            acc[i] = __builtin_amdgcn_mfma_f32_32x32x16_bf16(PA0, v0, acc[i], 0, 0, 0);
            short8 k1 = *(const short8*)(kp + (((4 * i + 2) ^ exr) << 3));
            short8 v1 = *(const short8*)(vp1 + i * 1024);
            nS = __builtin_amdgcn_mfma_f32_32x32x16_bf16(k1, qf[2 * i + 1], nS, 0, 0, 0);
            acc[i] = __builtin_amdgcn_mfma_f32_32x32x16_bf16(PA1, v1, acc[i], 0, 0, 0);
        }
        sS = nS;
        __builtin_amdgcn_s_waitcnt(0);   // K(t+2) + V(t+1) DMA complete
        __syncthreads();                 // all waves done reading V[cur], K[nxt]
        j0 += 32;
    }

    // ---- epilogue: tile 63 (cur = 1), no prefetch ----
    {
        short8 PA0, PA1;
        SOFTMAX_PACK(sS, PA0, PA1);
        const short* vp0 = Vlds + 16384 + voff0;
        const short* vp1 = Vlds + 16384 + voff1;
#pragma unroll
        for (int i = 0; i < 16; ++i) {
            short8 v0 = *(const short8*)(vp0 + i * 1024);
            acc[i] = __builtin_amdgcn_mfma_f32_32x32x16_bf16(PA0, v0, acc[i], 0, 0, 0);
            short8 v1 = *(const short8*)(vp1 + i * 1024);
            acc[i] = __builtin_amdgcn_mfma_f32_32x32x16_bf16(PA1, v1, acc[i], 0, 0, 0);
        }
    }
#undef STAGE_K
#undef STAGE_V
#undef SOFTMAX_PACK

    // ---- epilogue: unnormalized O -> bf16 partials; l reduce over hi-halves ----
    const float lt = lsum + __shfl_xor(lsum, 32, 64);
    ushort_t* pOut = (split ? pO1 : pO0) + ((long)bb * NSP + rows0) * CCH;
#pragma unroll
    for (int dt = 0; dt < 16; ++dt)
#pragma unroll
        for (int r = 0; r < 16; ++r) {
            const int rl = (r & 3) + 8 * (r >> 2) + 4 * hi;   // local row of O
            pOut[(long)rl * CCH + dt * 32 + l31] = f2b(acc[dt][r]);
        }
    if (hi == 0) {
        ml[(long)split * 4 * NSP + (long)bb * NSP + rows0 + l31] = lt;
    }

    // ---- fused merge: second arriver of the (bb, rg) pair merges its 128-row slab ----
    __threadfence();                 // release: partials + l device-visible
    __syncthreads();
    if (t == 0) arrived = atomicAdd(&flags[bb * 32 + rg], 1);
    __syncthreads();
    if (arrived == 1) {
        __threadfence();             // acquire
        ushort_t* p0 = pO0 + ((long)bb * NSP + rg * 128) * CCH;
        const ushort_t* p1 = pO1 + ((long)bb * NSP + rg * 128) * CCH;
        const float* l0 = ml + (long)bb * NSP + rg * 128;
        const float* l1 = l0 + (long)4 * NSP;
#pragma unroll 4
        for (int it = 0; it < 32; ++it) {
            const long f = ((long)it * 256 + t) * 8;   // over 128*512 elems
            const long row = f >> 9;
            const float inv = 1.f / (l0[row] + l1[row]);
            uint4 u0 = *(const uint4*)(p0 + f);
            uint4 u1 = *(const uint4*)(p1 + f);
            const unsigned int* a = (const unsigned int*)&u0;
            const unsigned int* b = (const unsigned int*)&u1;
            ushort_t outv[8] __attribute__((aligned(16)));
#pragma unroll
            for (int i = 0; i < 4; ++i) {
                float x0 = __uint_as_float(a[i] << 16), y0 = __uint_as_float(a[i] & 0xffff0000u);
                float x1 = __uint_as_float(b[i] << 16), y1 = __uint_as_float(b[i] & 0xffff0000u);
                outv[2 * i]     = f2b((x0 + x1) * inv);
                outv[2 * i + 1] = f2b((y0 + y1) * inv);
            }
            *(uint4*)(p0 + f) = *(uint4*)outv;
        }
    }
}

// ---------- host ----------
extern "C" void kernel_launch(void* const* d_in, const int* in_sizes, int n_in,
                              void* d_out, int out_size, void* d_ws, size_t ws_size,
                              hipStream_t stream) {
    const float* x   = (const float*)d_in[0];
    const float* gnw = (const float*)d_in[1];
    const float* gnb = (const float*)d_in[2];
    const float* qw  = (const float*)d_in[3];
    const float* qb  = (const float*)d_in[4];
    const float* kw  = (const float*)d_in[5];
    const float* kb  = (const float*)d_in[6];
    const float* vw  = (const float*)d_in[7];
    const float* vb  = (const float*)d_in[8];
    const float* pw  = (const float*)d_in[9];
    const float* pb  = (const float*)d_in[10];
    float* out = (float*)d_out;
    (void)in_sizes; (void)n_in; (void)out_size; (void)ws_size;

    const long E = (long)NSP * CCH;            // 2,097,152 elems per batch matrix
    // workspace (~86 MB)
    char* ws = (char*)d_ws;
    float*    mean = (float*)ws;               // 128 f32
    float*    rstd = (float*)(ws + 512);       // 128 f32
    ushort_t* wb   = (ushort_t*)(ws + 1024);   // [4][512*512] bf16 weights (2 MB)
    float*    sqb  = (float*)(wb + 4 * 262144);// 1024 f32 (qb*scl || kb)
    float*    ml   = sqb + 1024;               // [2][4*4096] f32 (128 KB)
    int*      flags = (int*)(ml + 2 * 4 * NSP);// 128 ints (split-merge rendezvous)
    ushort_t* ht   = (ushort_t*)(flags + 128); // [4][4096][512]; reused as pO1
    ushort_t* Kt   = ht + 4 * E;               // [4][4096][512]
    ushort_t* V    = Kt + 4 * E;               // [4][512][4096]
    ushort_t* Qt   = V  + 4 * E;               // [4][4096][512]  (pre-scaled by 512^-0.5)
    ushort_t* hOT  = Qt + 4 * E;               // [4][4096][512]; pO0 then merged O
    ushort_t* qwb = wb, *vwb = wb + 2 * 262144, *pwb = wb + 3 * 262144;

    // 0) zero the merge flags (graph-capture-legal async memset)
    hipMemsetAsync(flags, 0, 128 * sizeof(int), stream);
    // 1) prep: weight conversion + GroupNorm stats in one dispatch
    prep<<<dim3(256, 5), 256, 0, stream>>>(qw, kw, vw, pw, qb, kb, wb, sqb, x, mean, rstd);
    // 2) normalize + transpose
    norm_transpose<<<dim3(64, 8, 4), 256, 0, stream>>>(x, gnw, gnb, mean, rstd, ht);
    // 3) fused Q+K projection (N=1024, contiguous qwb||kwb, concat bias) + V projection
    gemm_tn<2, 0, 0, 1><<<dim3(8, 32, 4), 256, 0, stream>>>(ht, 512, E, qwb, 512, 0,
                                                            Qt, 512, E, sqb, nullptr, 0, 1.f, 512, Kt);
    gemm_tn<1, 0, 0, 0><<<dim3(32, 4, 4), 256, 0, stream>>>(vwb, 512, 0, ht, 512, E,
                                                            V, 4096, E, vb, nullptr, 0, 1.f, 512, nullptr);
    // 4) flash attention v9 + in-kernel split merge
    flash_attn<<<256, 256, 0, stream>>>(Qt, Kt, V, hOT, ht, ml, flags);
    // 5) out = x + pw @ h_out + pb
    gemm_tn<1, 1, 1, 0><<<dim3(32, 4, 4), 256, 0, stream>>>(pwb, 512, 0, hOT, 512, E,
                                                            out, 4096, E, pb, x, E, 1.f, 512, nullptr);
}

// Round 14
// 367.151 us; speedup vs baseline: 1.1144x; 1.1144x over previous
//
#include <hip/hip_runtime.h>
#include <hip/hip_bf16.h>
#include <stdint.h>

#define AS1 __attribute__((address_space(1)))
#define AS3 __attribute__((address_space(3)))

typedef unsigned short ushort_t;
typedef __attribute__((ext_vector_type(8))) short short8;
typedef __attribute__((ext_vector_type(4))) float floatx4;
typedef __attribute__((ext_vector_type(16))) float floatx16;
typedef __attribute__((ext_vector_type(2))) unsigned int uint2v;

// ---------- helpers ----------
__device__ __forceinline__ ushort_t f2b(float f) {
    union { float f; unsigned int i; } x; x.f = f;
    unsigned int r = x.i + 0x7fffu + ((x.i >> 16) & 1u);   // RNE
    return (ushort_t)(r >> 16);
}
__device__ __forceinline__ float b2f(ushort_t u) {
    union { unsigned int i; float f; } x; x.i = ((unsigned int)u) << 16; return x.f;
}
// async global->LDS, 16B per lane. LDS dest must be wave-uniform base + lane*16.
__device__ __forceinline__ void gl2lds16(const void* g, void* l) {
    __builtin_amdgcn_global_load_lds(
        (const AS1 unsigned int*)g,
        (AS3 unsigned int*)l,
        16, 0, 0);
}
// swap: a.hi-lanes <-> b.lo-lanes (both updated)
__device__ __forceinline__ void plswap(unsigned& a, unsigned& b) {
#if __has_builtin(__builtin_amdgcn_permlane32_swap)
    uint2v r = __builtin_amdgcn_permlane32_swap(a, b, false, false);
    a = r.x; b = r.y;
#else
    asm volatile("v_permlane32_swap_b32 %0, %1" : "+v"(a), "+v"(b));
#endif
}

static constexpr int CCH = 512;
static constexpr int NSP = 4096;   // 64*64 spatial
static constexpr int NG  = 32;

// ---------- kernel 1: GroupNorm stats ----------
__global__ __launch_bounds__(256) void gn_stats(const float* __restrict__ x,
                                                float* __restrict__ mean,
                                                float* __restrict__ rstd) {
    const long base = (long)blockIdx.x * 65536;
    const int t = threadIdx.x;
    float s1 = 0.f, s2 = 0.f;
    for (int i = t * 8; i < 65536; i += 256 * 8) {
        float4 a = *(const float4*)(x + base + i);
        float4 b = *(const float4*)(x + base + i + 4);
        s1 += a.x + a.y + a.z + a.w + b.x + b.y + b.z + b.w;
        s2 += a.x * a.x + a.y * a.y + a.z * a.z + a.w * a.w
            + b.x * b.x + b.y * b.y + b.z * b.z + b.w * b.w;
    }
#pragma unroll
    for (int o = 32; o; o >>= 1) { s1 += __shfl_xor(s1, o, 64); s2 += __shfl_xor(s2, o, 64); }
    __shared__ float r1[4], r2[4];
    const int lane = t & 63, wave = t >> 6;
    if (!lane) { r1[wave] = s1; r2[wave] = s2; }
    __syncthreads();
    if (!t) {
        float S1 = r1[0] + r1[1] + r1[2] + r1[3];
        float S2 = r2[0] + r2[1] + r2[2] + r2[3];
        float mu = S1 * (1.f / 65536.f);
        float var = S2 * (1.f / 65536.f) - mu * mu;
        mean[blockIdx.x] = mu;
        rstd[blockIdx.x] = rsqrtf(var + 1e-5f);
    }
}

// ---------- kernel 2: fp32 weights -> bf16; Q pre-scaled by 512^-0.5 ----------
// Also builds concatenated QK bias: sqb[0..511] = qb*scl, sqb[512..1023] = kb.
__global__ __launch_bounds__(256) void w_to_bf16(const float* __restrict__ q,
                                                 const float* __restrict__ k,
                                                 const float* __restrict__ v,
                                                 const float* __restrict__ p,
                                                 const float* __restrict__ qb,
                                                 const float* __restrict__ kb,
                                                 ushort_t* __restrict__ out,
                                                 float* __restrict__ sqb) {
    const float scl = 0.044194173824159216f;  // 512^-0.5
    const float* srcs[4] = { q, k, v, p };
    const float* s = srcs[blockIdx.y];
    const float m = (blockIdx.y == 0) ? scl : 1.f;
    const long i = ((long)blockIdx.x * 256 + threadIdx.x) * 4;
    float4 f = *(const float4*)(s + i);
    ushort_t o[4] __attribute__((aligned(8)));
    o[0] = f2b(f.x * m); o[1] = f2b(f.y * m); o[2] = f2b(f.z * m); o[3] = f2b(f.w * m);
    *(ushort4*)(out + (long)blockIdx.y * 262144 + i) = *(ushort4*)o;
    if (blockIdx.y == 0 && blockIdx.x == 0 && threadIdx.x < 128) {
        const int j = threadIdx.x * 4;
        float4 b = *(const float4*)(qb + j);
        sqb[j] = b.x * scl; sqb[j + 1] = b.y * scl; sqb[j + 2] = b.z * scl; sqb[j + 3] = b.w * scl;
    }
    if (blockIdx.y == 1 && blockIdx.x == 0 && threadIdx.x < 128) {
        const int j = threadIdx.x * 4;
        float4 b = *(const float4*)(kb + j);
        sqb[512 + j] = b.x; sqb[513 + j] = b.y; sqb[514 + j] = b.z; sqb[515 + j] = b.w;
    }
}

// ---------- kernel 3: normalize + transpose ----------
__global__ __launch_bounds__(256) void norm_transpose(const float* __restrict__ x,
                                                      const float* __restrict__ gw,
                                                      const float* __restrict__ gb,
                                                      const float* __restrict__ mean,
                                                      const float* __restrict__ rstd,
                                                      ushort_t* __restrict__ ht) {
    __shared__ ushort_t tile[64 * 65];
    const int b = blockIdx.z, c0 = blockIdx.y * 64, n0 = blockIdx.x * 64;
    const int t = threadIdx.x;
    const float* xb = x + ((long)b * CCH + c0) * NSP + n0;
#pragma unroll
    for (int p = 0; p < 2; ++p) {
        int li = p * 2048 + t * 8;
        int cl = li >> 6, nl = li & 63;
        int c = c0 + cl, g = c >> 4;
        float mu = mean[b * NG + g], rs = rstd[b * NG + g];
        float w  = gw[c] * rs;
        float bb = gb[c] - mu * w;
        float4 a = *(const float4*)(xb + (long)cl * NSP + nl);
        float4 d = *(const float4*)(xb + (long)cl * NSP + nl + 4);
        float f[8] = { a.x, a.y, a.z, a.w, d.x, d.y, d.z, d.w };
#pragma unroll
        for (int j = 0; j < 8; ++j) tile[cl * 65 + nl + j] = f2b(f[j] * w + bb);
    }
    __syncthreads();
#pragma unroll
    for (int p = 0; p < 2; ++p) {
        int li = p * 2048 + t * 8;
        int nl = li >> 6, cl = li & 63;
        ushort_t v[8] __attribute__((aligned(16)));
#pragma unroll
        for (int j = 0; j < 8; ++j) v[j] = tile[(cl + j) * 65 + nl];
        *(uint4*)(ht + ((long)b * NSP + n0 + nl) * CCH + c0 + cl) = *(uint4*)v;
    }
}

// ---------- GEMM: C[m][n] = scale * sum_k A[m][k]*B[n][k] (+bias)(+resid) ----------
// QK2: dual-output routing (n<512 -> Cp, else Cp2 at n-512); block-uniform branch.
template <int BIAS, int OUTF32, int RES, int QK2>
__global__ __launch_bounds__(256, 2) void gemm_tn(
    const ushort_t* __restrict__ A, int lda, long sA,
    const ushort_t* __restrict__ B, int ldb, long sB,
    void* __restrict__ Cp, int ldc, long sC,
    const float* __restrict__ bias,
    const float* __restrict__ resid, long sR,
    float scale, int K,
    void* __restrict__ Cp2) {
    __shared__ short As[128 * 32];
    __shared__ short Bs[128 * 32];
    const int t = threadIdx.x;
    const int lane = t & 63, wave = t >> 6;
    const long bz = blockIdx.z;
    const int m0 = blockIdx.y * 128, n0 = blockIdx.x * 128;

    const ushort_t* Ab = A + bz * sA + (long)(m0 + (t >> 2)) * lda + (t & 3) * 8;
    const ushort_t* Bb = B + bz * sB + (long)(n0 + (t >> 2)) * ldb + (t & 3) * 8;
    short* la = As + t * 8;
    short* lb = Bs + t * 8;

    const int wm = (wave & 1) * 64, wn = (wave >> 1) * 64;
    const int lm = lane & 15, lk = (lane >> 4) * 8;
    const short* pa = As + (wm + lm) * 32 + lk;
    const short* pb = Bs + (wn + lm) * 32 + lk;

    floatx4 acc[4][4];
#pragma unroll
    for (int i = 0; i < 4; ++i)
#pragma unroll
        for (int j = 0; j < 4; ++j) acc[i][j] = (floatx4){0.f, 0.f, 0.f, 0.f};

    for (int k0 = 0; k0 < K; k0 += 32) {
        __syncthreads();
        gl2lds16(Ab, la);
        gl2lds16(Ab + 64 * (long)lda, la + 64 * 32);
        gl2lds16(Bb, lb);
        gl2lds16(Bb + 64 * (long)ldb, lb + 64 * 32);
        Ab += 32; Bb += 32;
        __builtin_amdgcn_s_waitcnt(0);
        __syncthreads();
        short8 af[4], bfr[4];
#pragma unroll
        for (int i = 0; i < 4; ++i) af[i]  = *(const short8*)(pa + i * 16 * 32);
#pragma unroll
        for (int i = 0; i < 4; ++i) bfr[i] = *(const short8*)(pb + i * 16 * 32);
#pragma unroll
        for (int mi = 0; mi < 4; ++mi)
#pragma unroll
            for (int ni = 0; ni < 4; ++ni)
                acc[mi][ni] = __builtin_amdgcn_mfma_f32_16x16x32_bf16(af[mi], bfr[ni], acc[mi][ni], 0, 0, 0);
    }

    const int row4 = (lane >> 4) * 4;
    const int ncol = lane & 15;
#pragma unroll
    for (int mi = 0; mi < 4; ++mi) {
#pragma unroll
        for (int ni = 0; ni < 4; ++ni) {
            const int n = n0 + wn + ni * 16 + ncol;
            float bn = (BIAS == 2) ? bias[n] : 0.f;
#pragma unroll
            for (int r = 0; r < 4; ++r) {
                const int m = m0 + wm + mi * 16 + row4 + r;
                float v = acc[mi][ni][r] * scale;
                if (BIAS == 1) v += bias[m];
                if (BIAS == 2) v += bn;
                if (RES) v += resid[bz * sR + (long)m * ldc + n];
                if (QK2) {
                    const long idx = bz * sC + (long)m * ldc + (n & 511);
                    if (n < 512) ((ushort_t*)Cp)[idx]  = f2b(v);
                    else         ((ushort_t*)Cp2)[idx] = f2b(v);
                } else {
                    const long idx = bz * sC + (long)m * ldc + n;
                    if (OUTF32) ((float*)Cp)[idx] = v;
                    else        ((ushort_t*)Cp)[idx] = f2b(v);
                }
            }
        }
    }
}

// ---------- fused flash attention v9 (measured best; no setprio) ----------
// Grid 256 = 1 block/CU; 4 waves x 32 rows. Swapped 32x32x16 QK^T, in-register P.
// Pipeline: QK runs ONE TILE AHEAD of PV; per iteration the 32 PV(t) MFMAs and the
// 32 QK(t+1) MFMAs are interleaved (independent streams -> no C-dep stalls), and
// softmax(t) runs on S carried in registers from the previous iteration.
// Buffers: 2 K-slots + 2 V-slots; one vmcnt(0)+barrier per tile.
// Session A/B ledger: setprio -23us (r11); counted vmcnt -33us (r7); 3-slot K
// -74us (r6); V-from-L2 -15us (r9); 16-row waves -390us (r10). This form wins.
__global__ __launch_bounds__(256, 1) void flash_attn(const ushort_t* __restrict__ Qt,
                                                     const ushort_t* __restrict__ Kt,
                                                     const ushort_t* __restrict__ V,
                                                     ushort_t* __restrict__ pO0,
                                                     ushort_t* __restrict__ pO1,
                                                     float* __restrict__ ml) {
    __shared__ short Klds[2 * 16384];     // 2 x 32 KB: row j = 64 granules, granule g holds global g^(j&15)
    __shared__ short Vlds[2 * 16384];     // 2 x 32 KB: [d 0..511][32 j], granule mv holds global mv^((d>>1)&3)
    const int t = threadIdx.x;
    const int lane = t & 63, wave = t >> 6;
    const int l31 = lane & 31, hi = lane >> 5;
    const int blk = blockIdx.x;
    const int xcd = blk & 7;
    const int bb = xcd >> 1;
    const int split = xcd & 1;
    const int rows0 = (blk >> 3) * 128 + wave * 32;
    const int j_lo = split * 2048;

    // Q B-frags: B[n=row=l31][k=s*16+hi*8+e], 32 x short8 = 128 VGPR
    const ushort_t* Qb = Qt + ((long)bb * NSP + rows0 + l31) * CCH + hi * 8;
    short8 qf[32];
#pragma unroll
    for (int s = 0; s < 32; ++s) qf[s] = *(const short8*)(Qb + s * 16);

    floatx16 acc[16];
#pragma unroll
    for (int i = 0; i < 16; ++i)
        acc[i] = (floatx16){0.f,0.f,0.f,0.f,0.f,0.f,0.f,0.f,0.f,0.f,0.f,0.f,0.f,0.f,0.f,0.f};
    float lsum = 0.f;

    const ushort_t* KtB = Kt + (long)bb * NSP * CCH;   // [4096][512]
    const ushort_t* Vb  = V + (long)bb * NSP * CCH;    // [512][4096]

#define STAGE_K(buf, J0)                                                          \
    {                                                                             \
        short* kb_ = Klds + (buf) * 16384;                                        \
        _Pragma("unroll")                                                         \
        for (int i_ = 0; i_ < 8; ++i_) {                                          \
            const int ch_ = i_ * 256 + t;                                         \
            const int jr_ = ch_ >> 6, m_ = ch_ & 63;                              \
            const int ms_ = m_ ^ (jr_ & 15);                                      \
            gl2lds16(KtB + (long)((J0) + jr_) * CCH + ms_ * 8, kb_ + ch_ * 8);    \
        }                                                                         \
    }
#define STAGE_V(buf, J0)                                                          \
    {                                                                             \
        short* vb_ = Vlds + (buf) * 16384;                                        \
        _Pragma("unroll")                                                         \
        for (int i_ = 0; i_ < 8; ++i_) {                                          \
            const int g_ = i_ * 256 + t;                                          \
            const int d_ = g_ >> 2, mv_ = g_ & 3;                                 \
            const int js_ = (mv_ ^ ((d_ >> 1) & 3)) * 8;                          \
            gl2lds16(Vb + (long)d_ * NSP + (J0) + js_, vb_ + g_ * 8);             \
        }                                                                         \
    }

    // softmax on sS -> PA0/PA1 (j 0..15 / 16..31 slices), updates lsum
#define SOFTMAX_PACK(sS, PA0, PA1)                                                \
    {                                                                             \
        float pv_[16];                                                            \
        _Pragma("unroll")                                                         \
        for (int r = 0; r < 16; ++r) { pv_[r] = __expf((sS)[r] - 12.f); lsum += pv_[r]; } \
        unsigned pk[8];                                                           \
        _Pragma("unroll")                                                         \
        for (int g = 0; g < 4; ++g) {                                             \
            asm("v_cvt_pk_bf16_f32 %0, %1, %2" : "=v"(pk[2 * g])     : "v"(pv_[4 * g]),     "v"(pv_[4 * g + 1])); \
            asm("v_cvt_pk_bf16_f32 %0, %1, %2" : "=v"(pk[2 * g + 1]) : "v"(pv_[4 * g + 2]), "v"(pv_[4 * g + 3])); \
        }                                                                         \
        plswap(pk[0], pk[2]);                                                     \
        plswap(pk[1], pk[3]);                                                     \
        plswap(pk[4], pk[6]);                                                     \
        plswap(pk[5], pk[7]);                                                     \
        union { unsigned u[4]; short8 s8; } uA_, uB_;                             \
        uA_.u[0] = pk[0]; uA_.u[1] = pk[1]; uA_.u[2] = pk[2]; uA_.u[3] = pk[3];   \
        uB_.u[0] = pk[4]; uB_.u[1] = pk[5]; uB_.u[2] = pk[6]; uB_.u[3] = pk[7];   \
        (PA0) = uA_.s8; (PA1) = uB_.s8;                                           \
    }

    STAGE_K(0, j_lo);
    STAGE_V(0, j_lo);
    STAGE_K(1, j_lo + 32);          // K one tile ahead
    __builtin_amdgcn_s_waitcnt(0);
    __syncthreads();

    // K read swizzle: granule for k-chunk s = (2s+hi) ^ (l31&15) = (4*s2 [+2]) ^ exr
    const int exr = (l31 & 15) ^ hi;
    const short* kroot = Klds + l31 * 512;
    const int cv = (l31 >> 1) & 3;          // V read swizzle
    const int voff0 = l31 * 32 + ((hi ^ cv) << 3);
    const int voff1 = l31 * 32 + (((2 + hi) ^ cv) << 3);

    // ---- prologue: S(0) from K buf 0 ----
    floatx16 sS = (floatx16){0.f,0.f,0.f,0.f,0.f,0.f,0.f,0.f,0.f,0.f,0.f,0.f,0.f,0.f,0.f,0.f};
#pragma unroll
    for (int s2 = 0; s2 < 16; ++s2) {
        short8 k0 = *(const short8*)(kroot + (((4 * s2)     ^ exr) << 3));
        short8 k1 = *(const short8*)(kroot + (((4 * s2 + 2) ^ exr) << 3));
        sS = __builtin_amdgcn_mfma_f32_32x32x16_bf16(k0, qf[2 * s2],     sS, 0, 0, 0);
        sS = __builtin_amdgcn_mfma_f32_32x32x16_bf16(k1, qf[2 * s2 + 1], sS, 0, 0, 0);
    }
    __syncthreads();                 // all waves done with K buf 0 -> restageable

    int j0 = j_lo;
    for (int tile = 0; tile < 63; ++tile) {
        const int cur = tile & 1, nxt = cur ^ 1;
        if (tile < 62) STAGE_K(cur, j0 + 64);    // K(t+2) -> slot of K(t)
        STAGE_V(nxt, j0 + 32);                   // V(t+1) -> slot of V(t-1)

        short8 PA0, PA1;
        SOFTMAX_PACK(sS, PA0, PA1);

        // ---- interleaved: PV(t) from V[cur]  ||  QK(t+1) from K[nxt] ----
        const short* kp  = kroot + nxt * 16384;
        const short* vp0 = Vlds + cur * 16384 + voff0;
        const short* vp1 = Vlds + cur * 16384 + voff1;
        floatx16 nS = (floatx16){0.f,0.f,0.f,0.f,0.f,0.f,0.f,0.f,0.f,0.f,0.f,0.f,0.f,0.f,0.f,0.f};
#pragma unroll
        for (int i = 0; i < 16; ++i) {
            short8 k0 = *(const short8*)(kp + (((4 * i)     ^ exr) << 3));
            short8 v0 = *(const short8*)(vp0 + i * 1024);
            nS = __builtin_amdgcn_mfma_f32_32x32x16_bf16(k0, qf[2 * i], nS, 0, 0, 0);
            acc[i] = __builtin_amdgcn_mfma_f32_32x32x16_bf16(PA0, v0, acc[i], 0, 0, 0);
            short8 k1 = *(const short8*)(kp + (((4 * i + 2) ^ exr) << 3));
            short8 v1 = *(const short8*)(vp1 + i * 1024);
            nS = __builtin_amdgcn_mfma_f32_32x32x16_bf16(k1, qf[2 * i + 1], nS, 0, 0, 0);
            acc[i] = __builtin_amdgcn_mfma_f32_32x32x16_bf16(PA1, v1, acc[i], 0, 0, 0);
        }
        sS = nS;
        __builtin_amdgcn_s_waitcnt(0);   // K(t+2) + V(t+1) DMA complete
        __syncthreads();                 // all waves done reading V[cur], K[nxt]
        j0 += 32;
    }

    // ---- epilogue: tile 63 (cur = 1), no prefetch ----
    {
        short8 PA0, PA1;
        SOFTMAX_PACK(sS, PA0, PA1);
        const short* vp0 = Vlds + 16384 + voff0;
        const short* vp1 = Vlds + 16384 + voff1;
#pragma unroll
        for (int i = 0; i < 16; ++i) {
            short8 v0 = *(const short8*)(vp0 + i * 1024);
            acc[i] = __builtin_amdgcn_mfma_f32_32x32x16_bf16(PA0, v0, acc[i], 0, 0, 0);
            short8 v1 = *(const short8*)(vp1 + i * 1024);
            acc[i] = __builtin_amdgcn_mfma_f32_32x32x16_bf16(PA1, v1, acc[i], 0, 0, 0);
        }
    }
#undef STAGE_K
#undef STAGE_V
#undef SOFTMAX_PACK

    // ---- epilogue: unnormalized O -> bf16 partials; l reduce over hi-halves ----
    const float lt = lsum + __shfl_xor(lsum, 32, 64);
    ushort_t* pOut = (split ? pO1 : pO0) + ((long)bb * NSP + rows0) * CCH;
#pragma unroll
    for (int dt = 0; dt < 16; ++dt)
#pragma unroll
        for (int r = 0; r < 16; ++r) {
            const int rl = (r & 3) + 8 * (r >> 2) + 4 * hi;   // local row of O
            pOut[(long)rl * CCH + dt * 32 + l31] = f2b(acc[dt][r]);
        }
    if (hi == 0) {
        ml[(long)split * 4 * NSP + (long)bb * NSP + rows0 + l31] = lt;
    }
}

// ---------- merge: O = (pO0 + pO1) / (l0 + l1) ----------
__global__ __launch_bounds__(256) void merge_splits(ushort_t* __restrict__ pO0,
                                                    const ushort_t* __restrict__ pO1,
                                                    const float* __restrict__ ml) {
    const long f = ((long)blockIdx.x * 256 + threadIdx.x) * 8;   // over 4*4096*512
    const long row = f >> 9;
    const float inv = 1.f / (ml[row] + ml[(long)4 * NSP + row]);
    uint4 u0 = *(const uint4*)(pO0 + f);
    uint4 u1 = *(const uint4*)(pO1 + f);
    const unsigned int* a = (const unsigned int*)&u0;
    const unsigned int* b = (const unsigned int*)&u1;
    ushort_t out[8] __attribute__((aligned(16)));
#pragma unroll
    for (int i = 0; i < 4; ++i) {
        float x0 = __uint_as_float(a[i] << 16), y0 = __uint_as_float(a[i] & 0xffff0000u);
        float x1 = __uint_as_float(b[i] << 16), y1 = __uint_as_float(b[i] & 0xffff0000u);
        out[2 * i]     = f2b((x0 + x1) * inv);
        out[2 * i + 1] = f2b((y0 + y1) * inv);
    }
    *(uint4*)(pO0 + f) = *(uint4*)out;
}

// ---------- host ----------
extern "C" void kernel_launch(void* const* d_in, const int* in_sizes, int n_in,
                              void* d_out, int out_size, void* d_ws, size_t ws_size,
                              hipStream_t stream) {
    const float* x   = (const float*)d_in[0];
    const float* gnw = (const float*)d_in[1];
    const float* gnb = (const float*)d_in[2];
    const float* qw  = (const float*)d_in[3];
    const float* qb  = (const float*)d_in[4];
    const float* kw  = (const float*)d_in[5];
    const float* kb  = (const float*)d_in[6];
    const float* vw  = (const float*)d_in[7];
    const float* vb  = (const float*)d_in[8];
    const float* pw  = (const float*)d_in[9];
    const float* pb  = (const float*)d_in[10];
    float* out = (float*)d_out;
    (void)in_sizes; (void)n_in; (void)out_size; (void)ws_size;

    const long E = (long)NSP * CCH;            // 2,097,152 elems per batch matrix
    // workspace (~86 MB)
    char* ws = (char*)d_ws;
    float*    mean = (float*)ws;               // 128 f32
    float*    rstd = (float*)(ws + 512);       // 128 f32
    ushort_t* wb   = (ushort_t*)(ws + 1024);   // [4][512*512] bf16 weights (2 MB)
    float*    sqb  = (float*)(wb + 4 * 262144);// 1024 f32 (qb*scl || kb)
    float*    ml   = sqb + 1024;               // [2][4*4096] f32 (128 KB)
    ushort_t* ht   = (ushort_t*)(ml + 2 * 4 * NSP); // [4][4096][512]; reused as pO1
    ushort_t* Kt   = ht + 4 * E;               // [4][4096][512]
    ushort_t* V    = Kt + 4 * E;               // [4][512][4096]
    ushort_t* Qt   = V  + 4 * E;               // [4][4096][512]  (pre-scaled by 512^-0.5)
    ushort_t* hOT  = Qt + 4 * E;               // [4][4096][512]; pO0 then merged O
    ushort_t* qwb = wb, *vwb = wb + 2 * 262144, *pwb = wb + 3 * 262144;

    // 1) GroupNorm stats + weight conversion (also builds concat QK bias)
    gn_stats<<<128, 256, 0, stream>>>(x, mean, rstd);
    w_to_bf16<<<dim3(256, 4), 256, 0, stream>>>(qw, kw, vw, pw, qb, kb, wb, sqb);
    // 2) normalize + transpose
    norm_transpose<<<dim3(64, 8, 4), 256, 0, stream>>>(x, gnw, gnb, mean, rstd, ht);
    // 3) fused Q+K projection (N=1024, contiguous qwb||kwb, concat bias) + V projection
    gemm_tn<2, 0, 0, 1><<<dim3(8, 32, 4), 256, 0, stream>>>(ht, 512, E, qwb, 512, 0,
                                                            Qt, 512, E, sqb, nullptr, 0, 1.f, 512, Kt);
    gemm_tn<1, 0, 0, 0><<<dim3(32, 4, 4), 256, 0, stream>>>(vwb, 512, 0, ht, 512, E,
                                                            V, 4096, E, vb, nullptr, 0, 1.f, 512, nullptr);
    // 4) flash attention v9 (no setprio)
    flash_attn<<<256, 256, 0, stream>>>(Qt, Kt, V, hOT, ht, ml);
    merge_splits<<<4096, 256, 0, stream>>>(hOT, ht, ml);
    // 5) out = x + pw @ h_out + pb
    gemm_tn<1, 1, 1, 0><<<dim3(32, 4, 4), 256, 0, stream>>>(pwb, 512, 0, hOT, 512, E,
                                                            out, 4096, E, pb, x, E, 1.f, 512, nullptr);
}